// Round 5
// baseline (2416.706 us; speedup 1.0000x reference)
//
#include <hip/hip_runtime.h>
#include <hip/hip_bf16.h>
#include <cstdio>
#include <cstdint>

#define BS_   128
#define T_    128
#define A_    8
#define D_    128
#define H_    512
#define ROWS_ 1024           // BS*A
#define MTOT_ 131072         // BS*T*A
#define SLAB_ (ROWS_ * H_)   // one timestep of X, in elements

typedef __hip_bfloat16 bf16;
typedef __attribute__((ext_vector_type(4))) float f32x4;
typedef __attribute__((ext_vector_type(8))) short s16x8;
typedef __attribute__((ext_vector_type(4))) short s16x4;

// async global->LDS, 16B per lane; LDS dest is wave-uniform base + lane*16
__device__ __forceinline__ void async_ld16(const void* g, const void* lds) {
  __builtin_amdgcn_global_load_lds((const __attribute__((address_space(1))) void*)g,
                                   (__attribute__((address_space(3))) void*)lds,
                                   16, 0, 0);
}
__device__ __forceinline__ s16x8 ldg8(const short* p) { return *(const s16x8*)p; }
__device__ __forceinline__ float sigm(float x) { return 1.f / (1.f + __expf(-x)); }
__device__ __forceinline__ float tanh_f(float x) {
  const float e = __expf(2.f * x);            // inf-safe: x>>0 -> 1, x<<0 -> -1
  return 1.f - 2.f / (e + 1.f);
}
// coherent (L2-bypassing, agent-scope) 16B load as two 64-bit atomic loads
__device__ __forceinline__ s16x8 ldh8_agent(const short* p) {
  union { unsigned long long u[2]; s16x8 v; } c;
  c.u[0] = __hip_atomic_load((const unsigned long long*)p, __ATOMIC_RELAXED,
                             __HIP_MEMORY_SCOPE_AGENT);
  c.u[1] = __hip_atomic_load((const unsigned long long*)p + 1, __ATOMIC_RELAXED,
                             __HIP_MEMORY_SCOPE_AGENT);
  return c.v;
}

// fp32 -> bf16 conversion, 4 elts/thread
__global__ __launch_bounds__(256)
void cvt_kernel(const float* __restrict__ src, bf16* __restrict__ dst) {
  const int i = (blockIdx.x * 256 + threadIdx.x) << 2;
  const float4 v = *(const float4*)(src + i);
  s16x4 o;
  o[0] = __builtin_bit_cast(short, __float2bfloat16(v.x));
  o[1] = __builtin_bit_cast(short, __float2bfloat16(v.y));
  o[2] = __builtin_bit_cast(short, __float2bfloat16(v.z));
  o[3] = __builtin_bit_cast(short, __float2bfloat16(v.w));
  *(s16x4*)((short*)dst + i) = o;
}

// ---------------------------------------------------------------------------
// X = relu(obs @ W1^T + b1) for ALL timesteps, stored X[t][row][j] (row=b*8+a).
// ---------------------------------------------------------------------------
__global__ __launch_bounds__(256)
void xgemm_kernel(const bf16* __restrict__ Ag, const bf16* __restrict__ Wg,
                  const float* __restrict__ bias, bf16* __restrict__ Og) {
  const int bid = blockIdx.x;
  const int m0 = (bid >> 2) << 7;
  const int n0 = (bid & 3) << 7;
  const int tid = threadIdx.x;
  const int w = tid >> 6, lane = tid & 63;
  const int r = lane & 15, q = lane >> 4;
  const int wm = w & 1, wn = w >> 1;

  __shared__ short As[128 * 32];
  __shared__ short Bs[128 * 32];

  f32x4 acc[4][4];
  const f32x4 vz = {0.f, 0.f, 0.f, 0.f};
#pragma unroll
  for (int i = 0; i < 4; ++i)
#pragma unroll
    for (int j = 0; j < 4; ++j) acc[i][j] = vz;

  const int lrow = lane >> 2;
  const int kcol = (lane & 3) << 3;

  for (int kt = 0; kt < 4; ++kt) {          // K = 128
    __syncthreads();
    const int kbase = kt << 5;
#pragma unroll
    for (int jj = 0; jj < 2; ++jj) {
      const int c = (w << 1) + jj;
      const int m = (c << 4) + lrow;
      async_ld16(Ag + (size_t)(m0 + m) * D_ + kbase + kcol, &As[c << 9]);
      async_ld16(Wg + (size_t)(n0 + m) * D_ + kbase + kcol, &Bs[c << 9]);
    }
    __syncthreads();

    s16x8 af[4], bfr[4];
#pragma unroll
    for (int x = 0; x < 4; ++x) {
      af[x]  = *(const s16x8*)&As[((wm << 6) + (x << 4) + r) * 32 + (q << 3)];
      bfr[x] = *(const s16x8*)&Bs[((wn << 6) + (x << 4) + r) * 32 + (q << 3)];
    }
#pragma unroll
    for (int i = 0; i < 4; ++i)
#pragma unroll
      for (int j = 0; j < 4; ++j)
        acc[i][j] = __builtin_amdgcn_mfma_f32_16x16x32_bf16(af[i], bfr[j],
                                                            acc[i][j], 0, 0, 0);
  }

#pragma unroll
  for (int j = 0; j < 4; ++j) {
    const int gn = n0 + (wn << 6) + (j << 4) + r;
    const float bb = bias[gn];
#pragma unroll
    for (int i = 0; i < 4; ++i) {
      const int gmb = m0 + (wm << 6) + (i << 4) + (q << 2);
#pragma unroll
      for (int ii = 0; ii < 4; ++ii) {
        const int gm = gmb + ii;
        const float v = fmaxf(acc[i][j][ii] + bb, 0.f);
        const int b = gm >> 10, tt = (gm >> 3) & 127, a = gm & 7;
        Og[((size_t)tt * ROWS_ + (b << 3) + a) * (size_t)H_ + gn] =
            __float2bfloat16(v);
      }
    }
  }
}

// ---------------------------------------------------------------------------
// Persistent GRU scan, round-5 structure:
//  * 256 blocks x 256 thr; block (rt=bid&7, jt=bid>>3): rows rt*128..+127,
//    h-cols jt*16..+15. 96 KB dyn-LDS requested (48 used) -> 1 block/CU.
//  * Wih slice lane-packed in LDS: chunk (g,kt) holds exactly the 64 lanes'
//    B-fragments in lane order -> ds_read_b128 at base+lane*16, conflict-free.
//  * Whh B-fragments live in REGISTERS (48 x 16B, step-invariant).
//  * h read via agent-scope 64-bit atomic loads (L2-bypass -> coherent without
//    any acquire fence; X + Wih stay warm in L1/L2 all 128 steps).
//  * Barrier: release-fence(wbl2) -> atomicAdd bar[bid&63] (64 counters, 4-way
//    contention) -> gi(t+1) compute (barrier-shadowed) -> wave0's 64 lanes
//    poll all counters in parallel (__all) -> syncthreads. No invalidate.
// ---------------------------------------------------------------------------
__global__ __launch_bounds__(256, 1)
void scan_kernel(const bf16* __restrict__ Wih, const bf16* __restrict__ Whh,
                 const float* __restrict__ bih, const float* __restrict__ bhh,
                 const float* __restrict__ Wv, const bf16* __restrict__ X,
                 bf16* __restrict__ Hb0, bf16* __restrict__ Hb1,
                 float* __restrict__ Vws, unsigned* __restrict__ bar) {
  extern __shared__ short sm[];   // Wih lane-packed: 48 chunks x 512 shorts

  const int bid = blockIdx.x;
  const int rt = bid & 7, jt = bid >> 3;
  const int j0 = jt << 4;
  const int tid = threadIdx.x;
  const int w = tid >> 6, lane = tid & 63;
  const int r = lane & 15, q = lane >> 4;
  const int rw = (rt << 7) + (w << 5);   // wave's 32 rows

  // ---- stage Wih lane-packed (48 x 1KB chunks, 12/wave), once ----
#pragma unroll
  for (int i = 0; i < 12; ++i) {
    const int c = (i << 2) + w;          // 0..47
    const int g = c >> 4, kt = c & 15;
    // lane (q,r) fetches its own future B-fragment: row g*512+j0+r, k kt*32+q*8
    async_ld16(Wih + (size_t)((g << 9) + j0 + r) * H_ + (kt << 5) + (q << 3),
               sm + ((size_t)c << 9));
  }

  // ---- Whh B-fragments -> registers (step-invariant) ----
  s16x8 whhf[3][16];
#pragma unroll
  for (int g = 0; g < 3; ++g)
#pragma unroll
    for (int kt = 0; kt < 16; ++kt)
      whhf[g][kt] = ldg8((const short*)Whh
                         + (size_t)((g << 9) + j0 + r) * H_ + (kt << 5) + (q << 3));

  const int j = j0 + r;
  const float bR  = bih[j] + bhh[j];
  const float bZ  = bih[512 + j] + bhh[512 + j];
  const float bIN = bih[1024 + j];
  const float bHN = bhh[1024 + j];
  const float wvj = Wv[j];

  float hm[2][4] = {{0.f, 0.f, 0.f, 0.f}, {0.f, 0.f, 0.f, 0.f}};
  const f32x4 vz = {0.f, 0.f, 0.f, 0.f};

  const size_t aoff0 = (size_t)(rw + r) * H_ + (q << 3);
  const size_t aoff1 = aoff0 + (size_t)16 * H_;
  const short* Xs = (const short*)X;

  __syncthreads();   // Wih staged

  // ---- gi for t=0 (X slab 0), lane-packed LDS reads ----
  f32x4 gia[3][2];
#pragma unroll
  for (int g = 0; g < 3; ++g) { gia[g][0] = vz; gia[g][1] = vz; }
  {
    s16x8 ax[4][2];
#pragma unroll
    for (int p = 0; p < 3; ++p) {
      ax[p][0] = ldg8(Xs + aoff0 + (p << 5));
      ax[p][1] = ldg8(Xs + aoff1 + (p << 5));
    }
#pragma unroll
    for (int kt = 0; kt < 16; ++kt) {
      const int cur = kt & 3;
      if (kt < 13) {
        const int np = (kt + 3) & 3;
        ax[np][0] = ldg8(Xs + aoff0 + ((kt + 3) << 5));
        ax[np][1] = ldg8(Xs + aoff1 + ((kt + 3) << 5));
      }
#pragma unroll
      for (int g = 0; g < 3; ++g) {
        const s16x8 b = *(const s16x8*)&sm[(((g << 4) + kt) << 9) + (lane << 3)];
        gia[g][0] = __builtin_amdgcn_mfma_f32_16x16x32_bf16(ax[cur][0], b, gia[g][0], 0, 0, 0);
        gia[g][1] = __builtin_amdgcn_mfma_f32_16x16x32_bf16(ax[cur][1], b, gia[g][1], 0, 0, 0);
      }
    }
  }

  for (int t = 0; t < T_; ++t) {
    const short* hb = (const short*)((t & 1) ? Hb1 : Hb0);
    short* hn = (short*)((t & 1) ? Hb0 : Hb1);

    // ---- gh: full h-fragment burst (agent loads), register Whh ----
    s16x8 ah[16][2];
#pragma unroll
    for (int kt = 0; kt < 16; ++kt) {
      ah[kt][0] = ldh8_agent(hb + aoff0 + (kt << 5));
      ah[kt][1] = ldh8_agent(hb + aoff1 + (kt << 5));
    }
    f32x4 gha[3][2];
#pragma unroll
    for (int g = 0; g < 3; ++g) { gha[g][0] = vz; gha[g][1] = vz; }
#pragma unroll
    for (int kt = 0; kt < 16; ++kt)
#pragma unroll
      for (int g = 0; g < 3; ++g) {
        gha[g][0] = __builtin_amdgcn_mfma_f32_16x16x32_bf16(ah[kt][0], whhf[g][kt], gha[g][0], 0, 0, 0);
        gha[g][1] = __builtin_amdgcn_mfma_f32_16x16x32_bf16(ah[kt][1], whhf[g][kt], gha[g][1], 0, 0, 0);
      }

    // ---- gates, h update, value head ----
#pragma unroll
    for (int i = 0; i < 2; ++i)
#pragma unroll
      for (int ii = 0; ii < 4; ++ii) {
        const int row = rw + (i << 4) + (q << 2) + ii;
        const float rr = sigm(gia[0][i][ii] + gha[0][i][ii] + bR);
        const float zz = sigm(gia[1][i][ii] + gha[1][i][ii] + bZ);
        const float nn = tanh_f(gia[2][i][ii] + bIN + rr * (gha[2][i][ii] + bHN));
        const float hnew = (1.f - zz) * nn + zz * hm[i][ii];
        hm[i][ii] = hnew;
        hn[(size_t)row * H_ + j] = __builtin_bit_cast(short, __float2bfloat16(hnew));
        float vp = wvj * hnew;
        vp += __shfl_xor(vp, 1);
        vp += __shfl_xor(vp, 2);
        vp += __shfl_xor(vp, 4);
        vp += __shfl_xor(vp, 8);           // sum 16 j-lanes
        if (r == 0) atomicAdd(&Vws[t * ROWS_ + row], vp);
      }

    if (t == T_ - 1) break;

    // ---- barrier arrive (release) ----
    __syncthreads();                                        // all waves' stores drained
    if (w == 0) __builtin_amdgcn_fence(__ATOMIC_RELEASE, "agent");  // wbl2 (no inv)
    __syncthreads();
    if (tid == 0) atomicAdd(&bar[bid & 63], 1u);

    // ---- gi(t+1): barrier-shadowed (X read-only, L2-warm) ----
#pragma unroll
    for (int g = 0; g < 3; ++g) { gia[g][0] = vz; gia[g][1] = vz; }
    {
      const short* xb = Xs + (size_t)(t + 1) * SLAB_;
      s16x8 ax[4][2];
#pragma unroll
      for (int p = 0; p < 3; ++p) {
        ax[p][0] = ldg8(xb + aoff0 + (p << 5));
        ax[p][1] = ldg8(xb + aoff1 + (p << 5));
      }
#pragma unroll
      for (int kt = 0; kt < 16; ++kt) {
        const int cur = kt & 3;
        if (kt < 13) {
          const int np = (kt + 3) & 3;
          ax[np][0] = ldg8(xb + aoff0 + ((kt + 3) << 5));
          ax[np][1] = ldg8(xb + aoff1 + ((kt + 3) << 5));
        }
#pragma unroll
        for (int g = 0; g < 3; ++g) {
          const s16x8 b = *(const s16x8*)&sm[(((g << 4) + kt) << 9) + (lane << 3)];
          gia[g][0] = __builtin_amdgcn_mfma_f32_16x16x32_bf16(ax[cur][0], b, gia[g][0], 0, 0, 0);
          gia[g][1] = __builtin_amdgcn_mfma_f32_16x16x32_bf16(ax[cur][1], b, gia[g][1], 0, 0, 0);
        }
      }
    }

    // ---- barrier wait: 64 lanes poll 64 counters in parallel ----
    if (w == 0) {
      const unsigned tgt = (unsigned)(t + 1) << 2;          // 4 blocks per counter
      unsigned spins = 0;
      while (true) {
        const unsigned v = __hip_atomic_load(&bar[lane], __ATOMIC_RELAXED,
                                             __HIP_MEMORY_SCOPE_AGENT);
        if (__all(v >= tgt)) break;
        __builtin_amdgcn_s_sleep(2);
        if (++spins > 4000000u) break;                      // dead-man valve
      }
    }
    __syncthreads();   // no acquire fence: h loads below are L2-bypassing
  }
}

__global__ __launch_bounds__(256)
void init_kernel(bf16* __restrict__ Hb0, float* __restrict__ Vws,
                 unsigned* __restrict__ bar, const float* __restrict__ bv) {
  const int i = blockIdx.x * 256 + threadIdx.x;   // 0..524287
  Hb0[i] = __float2bfloat16(0.f);
  if (i < T_ * ROWS_) Vws[i] = bv[0];
  if (i < 64) bar[i] = 0u;
}

__global__ __launch_bounds__(256)
void out_kernel(const float* __restrict__ Vws, float* __restrict__ out) {
  const int o = blockIdx.x * 256 + threadIdx.x;   // [bs][T][A] flat
  const int b = o >> 10, tt = (o >> 3) & 127, a = o & 7;
  out[o] = Vws[tt * ROWS_ + (b << 3) + a];
}

extern "C" void kernel_launch(void* const* d_in, const int* in_sizes, int n_in,
                              void* d_out, int out_size, void* d_ws, size_t ws_size,
                              hipStream_t stream) {
  (void)in_sizes; (void)n_in; (void)out_size;
  const float* obs = (const float*)d_in[0];
  const float* W1  = (const float*)d_in[1];
  const float* b1  = (const float*)d_in[2];
  const float* Wih = (const float*)d_in[3];
  const float* bih = (const float*)d_in[4];
  const float* Whh = (const float*)d_in[5];
  const float* bhh = (const float*)d_in[6];
  const float* Wv  = (const float*)d_in[7];
  const float* bv  = (const float*)d_in[8];
  float* out = (float*)d_out;

  char* ws = (char*)d_ws;
  size_t off = 0;
  bf16*  X    = (bf16*)(ws + off);  off += (size_t)T_ * ROWS_ * H_ * 2;  // 128 MiB
  bf16*  obsB = (bf16*)(ws + off);  off += (size_t)MTOT_ * D_ * 2;       // 32 MiB
  bf16*  Hb0  = (bf16*)(ws + off);  off += (size_t)ROWS_ * H_ * 2;       // 1 MiB
  bf16*  Hb1  = (bf16*)(ws + off);  off += (size_t)ROWS_ * H_ * 2;       // 1 MiB
  float* Vws  = (float*)(ws + off); off += (size_t)T_ * ROWS_ * 4;       // 0.5 MiB
  bf16*  WihB = (bf16*)(ws + off);  off += (size_t)3 * H_ * H_ * 2;      // 1.5 MiB
  bf16*  WhhB = (bf16*)(ws + off);  off += (size_t)3 * H_ * H_ * 2;      // 1.5 MiB
  bf16*  W1B  = (bf16*)(ws + off);  off += (size_t)H_ * D_ * 2;          // 128 KiB
  unsigned* bar = (unsigned*)(ws + off); off += 256;                     // 64 ctrs
  if (ws_size < off) {
    fprintf(stderr, "[kernel_launch] WS TOO SMALL: need %zu have %zu\n", off, ws_size);
    fflush(stderr);
  }

  hipFuncSetAttribute((const void*)scan_kernel,
                      hipFuncAttributeMaxDynamicSharedMemorySize, 98304);

  cvt_kernel<<<768, 256, 0, stream>>>(Wih, WihB);        // 786432 elts
  cvt_kernel<<<768, 256, 0, stream>>>(Whh, WhhB);
  cvt_kernel<<<64, 256, 0, stream>>>(W1, W1B);           // 65536 elts
  cvt_kernel<<<16384, 256, 0, stream>>>(obs, obsB);      // 16.8M elts
  init_kernel<<<2048, 256, 0, stream>>>(Hb0, Vws, bar, bv);
  xgemm_kernel<<<4096, 256, 0, stream>>>(obsB, W1B, b1, X);
  // request 96 KB dyn-LDS (48 used) to pin 1 block/CU for the persistent grid
  scan_kernel<<<256, 256, 98304, stream>>>(WihB, WhhB, bih, bhh, Wv, X,
                                           Hb0, Hb1, Vws, bar);
  out_kernel<<<MTOT_ / 256, 256, 0, stream>>>(Vws, out);
}

// Round 6
// 1844.848 us; speedup vs baseline: 1.3100x; 1.3100x over previous
//
#include <hip/hip_runtime.h>
#include <hip/hip_bf16.h>
#include <cstdio>
#include <cstdint>

#define BS_   128
#define T_    128
#define A_    8
#define D_    128
#define H_    512
#define ROWS_ 1024           // BS*A
#define MTOT_ 131072         // BS*T*A
#define SLAB_ (ROWS_ * H_)   // one timestep slab (X or h), elements

typedef __hip_bfloat16 bf16;
typedef __attribute__((ext_vector_type(4))) float f32x4;
typedef __attribute__((ext_vector_type(8))) short s16x8;
typedef __attribute__((ext_vector_type(4))) short s16x4;

// async global->LDS, 16B per lane; LDS dest is wave-uniform base + lane*16
__device__ __forceinline__ void async_ld16(const void* g, const void* lds) {
  __builtin_amdgcn_global_load_lds((const __attribute__((address_space(1))) void*)g,
                                   (__attribute__((address_space(3))) void*)lds,
                                   16, 0, 0);
}
__device__ __forceinline__ s16x8 ldg8(const short* p) { return *(const s16x8*)p; }
__device__ __forceinline__ float sigm(float x) { return 1.f / (1.f + __expf(-x)); }
__device__ __forceinline__ float tanh_f(float x) {
  const float e = __expf(2.f * x);            // inf-safe
  return 1.f - 2.f / (e + 1.f);
}
// load 8 consecutive fp32, round to bf16 fragment
__device__ __forceinline__ s16x8 cvt8(const float* p) {
  const float4 a = ((const float4*)p)[0];
  const float4 b = ((const float4*)p)[1];
  s16x8 r_;
  r_[0] = __builtin_bit_cast(short, __float2bfloat16(a.x));
  r_[1] = __builtin_bit_cast(short, __float2bfloat16(a.y));
  r_[2] = __builtin_bit_cast(short, __float2bfloat16(a.z));
  r_[3] = __builtin_bit_cast(short, __float2bfloat16(a.w));
  r_[4] = __builtin_bit_cast(short, __float2bfloat16(b.x));
  r_[5] = __builtin_bit_cast(short, __float2bfloat16(b.y));
  r_[6] = __builtin_bit_cast(short, __float2bfloat16(b.z));
  r_[7] = __builtin_bit_cast(short, __float2bfloat16(b.w));
  return r_;
}

// obs [b][t][a][d] fp32 -> obsB [t][b*8+a][d] bf16, 4 elts/thread
__global__ __launch_bounds__(256)
void cvt_obs_kernel(const float* __restrict__ src, bf16* __restrict__ dst) {
  const int o = (blockIdx.x * 256 + threadIdx.x) << 2;
  const int d = o & 127, a = (o >> 7) & 7, t = (o >> 10) & 127, b = o >> 17;
  const float4 v = *(const float4*)(src + o);
  s16x4 pk;
  pk[0] = __builtin_bit_cast(short, __float2bfloat16(v.x));
  pk[1] = __builtin_bit_cast(short, __float2bfloat16(v.y));
  pk[2] = __builtin_bit_cast(short, __float2bfloat16(v.z));
  pk[3] = __builtin_bit_cast(short, __float2bfloat16(v.w));
  *(s16x4*)((short*)dst + ((((size_t)t << 10) + (b << 3) + a) << 7) + d) = pk;
}

// generic fp32 -> bf16, 4 elts/thread (W1)
__global__ __launch_bounds__(256)
void cvt_kernel(const float* __restrict__ src, bf16* __restrict__ dst) {
  const int i = (blockIdx.x * 256 + threadIdx.x) << 2;
  const float4 v = *(const float4*)(src + i);
  s16x4 o;
  o[0] = __builtin_bit_cast(short, __float2bfloat16(v.x));
  o[1] = __builtin_bit_cast(short, __float2bfloat16(v.y));
  o[2] = __builtin_bit_cast(short, __float2bfloat16(v.z));
  o[3] = __builtin_bit_cast(short, __float2bfloat16(v.w));
  *(s16x4*)((short*)dst + i) = o;
}

// out = bv (value-head bias broadcast; scan accumulates on top); zero barriers
__global__ __launch_bounds__(256)
void out_init_kernel(float* __restrict__ out, const float* __restrict__ bv,
                     unsigned* __restrict__ bar) {
  const int o = blockIdx.x * 256 + threadIdx.x;   // 0..131071
  out[o] = bv[0];
  if (o < 1024) bar[o] = 0u;
}

// ---------------------------------------------------------------------------
// X = relu(obsB @ W1^T + b1), A rows already in [t][row] order -> trivial epi.
// ---------------------------------------------------------------------------
__global__ __launch_bounds__(256)
void xgemm_kernel(const bf16* __restrict__ Ag, const bf16* __restrict__ Wg,
                  const float* __restrict__ bias, bf16* __restrict__ Og) {
  const int bid = blockIdx.x;
  const int m0 = (bid >> 2) << 7;
  const int n0 = (bid & 3) << 7;
  const int tid = threadIdx.x;
  const int w = tid >> 6, lane = tid & 63;
  const int r = lane & 15, q = lane >> 4;
  const int wm = w & 1, wn = w >> 1;

  __shared__ short As[128 * 32];
  __shared__ short Bs[128 * 32];

  f32x4 acc[4][4];
  const f32x4 vz = {0.f, 0.f, 0.f, 0.f};
#pragma unroll
  for (int i = 0; i < 4; ++i)
#pragma unroll
    for (int j = 0; j < 4; ++j) acc[i][j] = vz;

  const int lrow = lane >> 2;
  const int kcol = (lane & 3) << 3;

  for (int kt = 0; kt < 4; ++kt) {          // K = 128
    __syncthreads();
    const int kbase = kt << 5;
#pragma unroll
    for (int jj = 0; jj < 2; ++jj) {
      const int c = (w << 1) + jj;
      const int m = (c << 4) + lrow;
      async_ld16(Ag + (size_t)(m0 + m) * D_ + kbase + kcol, &As[c << 9]);
      async_ld16(Wg + (size_t)(n0 + m) * D_ + kbase + kcol, &Bs[c << 9]);
    }
    __syncthreads();

    s16x8 af[4], bfr[4];
#pragma unroll
    for (int x = 0; x < 4; ++x) {
      af[x]  = *(const s16x8*)&As[((wm << 6) + (x << 4) + r) * 32 + (q << 3)];
      bfr[x] = *(const s16x8*)&Bs[((wn << 6) + (x << 4) + r) * 32 + (q << 3)];
    }
#pragma unroll
    for (int i = 0; i < 4; ++i)
#pragma unroll
      for (int j = 0; j < 4; ++j)
        acc[i][j] = __builtin_amdgcn_mfma_f32_16x16x32_bf16(af[i], bfr[j],
                                                            acc[i][j], 0, 0, 0);
  }

#pragma unroll
  for (int j = 0; j < 4; ++j) {
    const int gn = n0 + (wn << 6) + (j << 4) + r;
    const float bb = bias[gn];
#pragma unroll
    for (int i = 0; i < 4; ++i) {
      const int gmb = m0 + (wm << 6) + (i << 4) + (q << 2);
#pragma unroll
      for (int ii = 0; ii < 4; ++ii) {
        const int gm = gmb + ii;
        Og[(size_t)gm * H_ + gn] =
            __float2bfloat16(fmaxf(acc[i][j][ii] + bb, 0.f));
      }
    }
  }
}

// ---------------------------------------------------------------------------
// Persistent GRU scan, round-6 coherence design:
//  * h t-indexed (Hseq[t], 127 slabs): every h address written once (step t),
//    read once (step t+1) -> reader L1/L2 can never be stale (virgin addrs;
//    kernel-boundary acquire invalidated pre-scan copies).
//  * h STORES: relaxed agent-scope 4B atomic stores (L3-direct, pipelined,
//    lane-pair packed) -> cross-XCD visible with NO fence, NO XCD assumption.
//  * h LOADS: plain dwordx4 (clustered burst; L3 once then L2-shared among the
//    32 same-rt blocks -- bid&7 XCD heuristic is perf-only).
//  * order: stores -> __syncthreads (vmcnt0 drain) -> arrive -> [gi shadow]
//    -> poll -> __syncthreads -> loads.
//  * Wih fp32->bf16 lane-packed into LDS once; Whh fp32->bf16 into registers.
//  * value head: shfl-reduce + atomicAdd straight into d_out (pre-set to bv).
// ---------------------------------------------------------------------------
__global__ __launch_bounds__(256, 1)
void scan_kernel(const float* __restrict__ Wih32, const float* __restrict__ Whh32,
                 const float* __restrict__ bih, const float* __restrict__ bhh,
                 const float* __restrict__ Wv, const bf16* __restrict__ X,
                 bf16* __restrict__ Hseq, float* __restrict__ out,
                 unsigned* __restrict__ bar) {
  extern __shared__ short sm[];   // Wih lane-packed: 48 chunks x 512 shorts

  const int bid = blockIdx.x;
  const int rt = bid & 7, jt = bid >> 3;
  const int j0 = jt << 4;
  const int tid = threadIdx.x;
  const int w = tid >> 6, lane = tid & 63;
  const int r = lane & 15, q = lane >> 4;
  const int rw = (rt << 7) + (w << 5);   // wave's 32 rows

  // ---- Wih slice fp32 -> bf16, lane-packed into LDS (once) ----
#pragma unroll
  for (int i = 0; i < 12; ++i) {
    const int c = (i << 2) + w;          // chunk 0..47 = (g, kt)
    const int g = c >> 4, kt = c & 15;
    const s16x8 v = cvt8(Wih32 + (size_t)((g << 9) + j0 + r) * H_
                               + (kt << 5) + (q << 3));
    *(s16x8*)&sm[(c << 9) + (lane << 3)] = v;   // ds_write_b128, conflict-free
  }

  // ---- Whh B-fragments fp32 -> bf16 registers (step-invariant) ----
  s16x8 whhf[3][16];
#pragma unroll
  for (int g = 0; g < 3; ++g)
#pragma unroll
    for (int kt = 0; kt < 16; ++kt)
      whhf[g][kt] = cvt8(Whh32 + (size_t)((g << 9) + j0 + r) * H_
                               + (kt << 5) + (q << 3));

  const int j = j0 + r;
  const float bR  = bih[j] + bhh[j];
  const float bZ  = bih[512 + j] + bhh[512 + j];
  const float bIN = bih[1024 + j];
  const float bHN = bhh[1024 + j];
  const float wvj = Wv[j];

  float hm[2][4] = {{0.f, 0.f, 0.f, 0.f}, {0.f, 0.f, 0.f, 0.f}};
  const f32x4 vz = {0.f, 0.f, 0.f, 0.f};

  const size_t aoff0 = (size_t)(rw + r) * H_ + (q << 3);
  const size_t aoff1 = aoff0 + (size_t)16 * H_;
  const short* Xs = (const short*)X;
  short* Hs = (short*)Hseq;

  __syncthreads();   // LDS staged

  // ---- gi for t=0 ----
  f32x4 gia[3][2];
#pragma unroll
  for (int g = 0; g < 3; ++g) { gia[g][0] = vz; gia[g][1] = vz; }
  {
    s16x8 ax[4][2];
#pragma unroll
    for (int p = 0; p < 3; ++p) {
      ax[p][0] = ldg8(Xs + aoff0 + (p << 5));
      ax[p][1] = ldg8(Xs + aoff1 + (p << 5));
    }
#pragma unroll
    for (int kt = 0; kt < 16; ++kt) {
      const int cur = kt & 3;
      if (kt < 13) {
        const int np = (kt + 3) & 3;
        ax[np][0] = ldg8(Xs + aoff0 + ((kt + 3) << 5));
        ax[np][1] = ldg8(Xs + aoff1 + ((kt + 3) << 5));
      }
#pragma unroll
      for (int g = 0; g < 3; ++g) {
        const s16x8 b = *(const s16x8*)&sm[(((g << 4) + kt) << 9) + (lane << 3)];
        gia[g][0] = __builtin_amdgcn_mfma_f32_16x16x32_bf16(ax[cur][0], b, gia[g][0], 0, 0, 0);
        gia[g][1] = __builtin_amdgcn_mfma_f32_16x16x32_bf16(ax[cur][1], b, gia[g][1], 0, 0, 0);
      }
    }
  }

  for (int t = 0; t < T_; ++t) {
    // ---- gh from Hseq[t-1]: plain clustered loads + register Whh ----
    f32x4 gha[3][2];
#pragma unroll
    for (int g = 0; g < 3; ++g) { gha[g][0] = vz; gha[g][1] = vz; }
    if (t > 0) {
      const short* hb = Hs + (size_t)(t - 1) * SLAB_;
      s16x8 ah[16][2];
#pragma unroll
      for (int kt = 0; kt < 16; ++kt) {
        ah[kt][0] = ldg8(hb + aoff0 + (kt << 5));
        ah[kt][1] = ldg8(hb + aoff1 + (kt << 5));
      }
#pragma unroll
      for (int kt = 0; kt < 16; ++kt)
#pragma unroll
        for (int g = 0; g < 3; ++g) {
          gha[g][0] = __builtin_amdgcn_mfma_f32_16x16x32_bf16(ah[kt][0], whhf[g][kt], gha[g][0], 0, 0, 0);
          gha[g][1] = __builtin_amdgcn_mfma_f32_16x16x32_bf16(ah[kt][1], whhf[g][kt], gha[g][1], 0, 0, 0);
        }
    }

    // ---- gates, h update, value head, L3-direct h store ----
    short* hrow = Hs + (size_t)t * SLAB_;
#pragma unroll
    for (int i = 0; i < 2; ++i)
#pragma unroll
      for (int ii = 0; ii < 4; ++ii) {
        const int row = rw + (i << 4) + (q << 2) + ii;
        const float rr = sigm(gia[0][i][ii] + gha[0][i][ii] + bR);
        const float zz = sigm(gia[1][i][ii] + gha[1][i][ii] + bZ);
        const float nn = tanh_f(gia[2][i][ii] + bIN + rr * (gha[2][i][ii] + bHN));
        const float hnew = (1.f - zz) * nn + zz * hm[i][ii];
        hm[i][ii] = hnew;
        // pack lane pair (cols j, j^1) into one 4B agent store (L3-direct)
        const unsigned hv =
            (unsigned)(unsigned short)__builtin_bit_cast(unsigned short,
                                                         __float2bfloat16(hnew));
        const unsigned pv = (unsigned)__shfl_xor((int)hv, 1);
        if (t < T_ - 1 && !(r & 1)) {
          const unsigned pk = hv | (pv << 16);
          __hip_atomic_store((unsigned*)(hrow + (size_t)row * H_ + j0 + r), pk,
                             __ATOMIC_RELAXED, __HIP_MEMORY_SCOPE_AGENT);
        }
        float vp = wvj * hnew;
        vp += __shfl_xor(vp, 1);
        vp += __shfl_xor(vp, 2);
        vp += __shfl_xor(vp, 4);
        vp += __shfl_xor(vp, 8);           // sum 16 j-lanes
        if (r == 0)                        // out[b][t][a] += partial
          atomicAdd(&out[((row >> 3) << 10) + (t << 3) + (row & 7)], vp);
      }

    if (t == T_ - 1) break;

    // ---- arrive: stores drained by syncthreads' vmcnt(0), then flag ----
    __syncthreads();
    if (tid == 0) atomicAdd(&bar[(bid & 63) << 4], 1u);   // 64 padded counters

    // ---- gi(t+1): barrier-shadowed ----
#pragma unroll
    for (int g = 0; g < 3; ++g) { gia[g][0] = vz; gia[g][1] = vz; }
    {
      const short* xb = Xs + (size_t)(t + 1) * SLAB_;
      s16x8 ax[4][2];
#pragma unroll
      for (int p = 0; p < 3; ++p) {
        ax[p][0] = ldg8(xb + aoff0 + (p << 5));
        ax[p][1] = ldg8(xb + aoff1 + (p << 5));
      }
#pragma unroll
      for (int kt = 0; kt < 16; ++kt) {
        const int cur = kt & 3;
        if (kt < 13) {
          const int np = (kt + 3) & 3;
          ax[np][0] = ldg8(xb + aoff0 + ((kt + 3) << 5));
          ax[np][1] = ldg8(xb + aoff1 + ((kt + 3) << 5));
        }
#pragma unroll
        for (int g = 0; g < 3; ++g) {
          const s16x8 b = *(const s16x8*)&sm[(((g << 4) + kt) << 9) + (lane << 3)];
          gia[g][0] = __builtin_amdgcn_mfma_f32_16x16x32_bf16(ax[cur][0], b, gia[g][0], 0, 0, 0);
          gia[g][1] = __builtin_amdgcn_mfma_f32_16x16x32_bf16(ax[cur][1], b, gia[g][1], 0, 0, 0);
        }
      }
    }

    // ---- wait: wave0's 64 lanes poll the 64 padded counters ----
    if (w == 0) {
      const unsigned tgt = (unsigned)(t + 1) << 2;          // 4 blocks/counter
      unsigned spins = 0;
      while (true) {
        const unsigned v = __hip_atomic_load(&bar[lane << 4], __ATOMIC_RELAXED,
                                             __HIP_MEMORY_SCOPE_AGENT);
        if (__all(v >= tgt)) break;
        __builtin_amdgcn_s_sleep(2);
        if (++spins > 4000000u) break;                      // dead-man valve
      }
    }
    __syncthreads();
  }
}

extern "C" void kernel_launch(void* const* d_in, const int* in_sizes, int n_in,
                              void* d_out, int out_size, void* d_ws, size_t ws_size,
                              hipStream_t stream) {
  (void)in_sizes; (void)n_in; (void)out_size;
  const float* obs = (const float*)d_in[0];
  const float* W1  = (const float*)d_in[1];
  const float* b1  = (const float*)d_in[2];
  const float* Wih = (const float*)d_in[3];
  const float* bih = (const float*)d_in[4];
  const float* Whh = (const float*)d_in[5];
  const float* bhh = (const float*)d_in[6];
  const float* Wv  = (const float*)d_in[7];
  const float* bv  = (const float*)d_in[8];
  float* out = (float*)d_out;

  // ws budget (256 MiB known from round-3 poison counters):
  //   Hseq 127 slabs x 1 MiB = 127 MiB  [slabs 0..31 alias obsB, slab 32
  //     aliases W1B -- both dead before scan writes h there]
  //   X    128 slabs x 1 MiB = 128 MiB
  //   bar  64 padded counters (4 KiB)
  char* ws = (char*)d_ws;
  bf16*  Hseq = (bf16*)ws;                                  // 127 MiB
  bf16*  obsB = Hseq;                                       // alias slabs 0..31
  bf16*  W1B  = Hseq + (size_t)32 * SLAB_;                  // alias slab 32
  bf16*  X    = (bf16*)(ws + (size_t)127 * SLAB_ * 2);      // 128 MiB
  unsigned* bar = (unsigned*)(ws + (size_t)255 * SLAB_ * 2);
  const size_t need = (size_t)255 * SLAB_ * 2 + 4096;
  if (ws_size < need) {
    fprintf(stderr, "[kernel_launch] WS TOO SMALL: need %zu have %zu\n",
            need, ws_size);
    fflush(stderr);
  }

  hipFuncSetAttribute((const void*)scan_kernel,
                      hipFuncAttributeMaxDynamicSharedMemorySize, 98304);

  cvt_obs_kernel<<<16384, 256, 0, stream>>>(obs, obsB);   // 16.8M elts
  cvt_kernel<<<64, 256, 0, stream>>>(W1, W1B);            // 65536 elts
  out_init_kernel<<<512, 256, 0, stream>>>(out, bv, bar);
  xgemm_kernel<<<4096, 256, 0, stream>>>(obsB, W1B, b1, X);
  // 96 KB dyn-LDS request (48 used) pins 1 block/CU -> 256 co-resident blocks
  scan_kernel<<<256, 256, 98304, stream>>>(Wih, Whh, bih, bhh, Wv, X,
                                           Hseq, out, bar);
}

// Round 7
// 1791.121 us; speedup vs baseline: 1.3493x; 1.0300x over previous
//
#include <hip/hip_runtime.h>
#include <hip/hip_bf16.h>
#include <cstdio>
#include <cstdint>

#define BS_   128
#define T_    128
#define A_    8
#define D_    128
#define H_    512
#define ROWS_ 1024           // BS*A
#define MTOT_ 131072         // BS*T*A
#define SLAB_ (ROWS_ * H_)   // one timestep slab (X or h), elements

typedef __hip_bfloat16 bf16;
typedef __attribute__((ext_vector_type(4))) float f32x4;
typedef __attribute__((ext_vector_type(8))) short s16x8;
typedef __attribute__((ext_vector_type(4))) short s16x4;

__device__ __forceinline__ void async_ld16(const void* g, const void* lds) {
  __builtin_amdgcn_global_load_lds((const __attribute__((address_space(1))) void*)g,
                                   (__attribute__((address_space(3))) void*)lds,
                                   16, 0, 0);
}
__device__ __forceinline__ s16x8 ldg8(const short* p) { return *(const s16x8*)p; }
__device__ __forceinline__ float sigm(float x) { return 1.f / (1.f + __expf(-x)); }
__device__ __forceinline__ float tanh_f(float x) {
  const float e = __expf(2.f * x);            // inf-safe
  return 1.f - 2.f / (e + 1.f);
}
__device__ __forceinline__ s16x8 cvt8(const float* p) {
  const float4 a = ((const float4*)p)[0];
  const float4 b = ((const float4*)p)[1];
  s16x8 r_;
  r_[0] = __builtin_bit_cast(short, __float2bfloat16(a.x));
  r_[1] = __builtin_bit_cast(short, __float2bfloat16(a.y));
  r_[2] = __builtin_bit_cast(short, __float2bfloat16(a.z));
  r_[3] = __builtin_bit_cast(short, __float2bfloat16(a.w));
  r_[4] = __builtin_bit_cast(short, __float2bfloat16(b.x));
  r_[5] = __builtin_bit_cast(short, __float2bfloat16(b.y));
  r_[6] = __builtin_bit_cast(short, __float2bfloat16(b.z));
  r_[7] = __builtin_bit_cast(short, __float2bfloat16(b.w));
  return r_;
}

// obs [b][t][a][d] fp32 -> obsB [t][b*8+a][d] bf16
__global__ __launch_bounds__(256)
void cvt_obs_kernel(const float* __restrict__ src, bf16* __restrict__ dst) {
  const int o = (blockIdx.x * 256 + threadIdx.x) << 2;
  const int d = o & 127, a = (o >> 7) & 7, t = (o >> 10) & 127, b = o >> 17;
  const float4 v = *(const float4*)(src + o);
  s16x4 pk;
  pk[0] = __builtin_bit_cast(short, __float2bfloat16(v.x));
  pk[1] = __builtin_bit_cast(short, __float2bfloat16(v.y));
  pk[2] = __builtin_bit_cast(short, __float2bfloat16(v.z));
  pk[3] = __builtin_bit_cast(short, __float2bfloat16(v.w));
  *(s16x4*)((short*)dst + ((((size_t)t << 10) + (b << 3) + a) << 7) + d) = pk;
}

__global__ __launch_bounds__(256)
void cvt_kernel(const float* __restrict__ src, bf16* __restrict__ dst) {
  const int i = (blockIdx.x * 256 + threadIdx.x) << 2;
  const float4 v = *(const float4*)(src + i);
  s16x4 o;
  o[0] = __builtin_bit_cast(short, __float2bfloat16(v.x));
  o[1] = __builtin_bit_cast(short, __float2bfloat16(v.y));
  o[2] = __builtin_bit_cast(short, __float2bfloat16(v.z));
  o[3] = __builtin_bit_cast(short, __float2bfloat16(v.w));
  *(s16x4*)((short*)dst + i) = o;
}

__global__ __launch_bounds__(256)
void bar_init_kernel(unsigned* __restrict__ bar) {
  const int i = blockIdx.x * 256 + threadIdx.x;
  if (i < 1024) bar[i] = 0u;
}

// ---------------------------------------------------------------------------
// X = relu(obsB @ W1^T + b1)
// ---------------------------------------------------------------------------
__global__ __launch_bounds__(256)
void xgemm_kernel(const bf16* __restrict__ Ag, const bf16* __restrict__ Wg,
                  const float* __restrict__ bias, bf16* __restrict__ Og) {
  const int bid = blockIdx.x;
  const int m0 = (bid >> 2) << 7;
  const int n0 = (bid & 3) << 7;
  const int tid = threadIdx.x;
  const int w = tid >> 6, lane = tid & 63;
  const int r = lane & 15, q = lane >> 4;
  const int wm = w & 1, wn = w >> 1;

  __shared__ short As[128 * 32];
  __shared__ short Bs[128 * 32];

  f32x4 acc[4][4];
  const f32x4 vz = {0.f, 0.f, 0.f, 0.f};
#pragma unroll
  for (int i = 0; i < 4; ++i)
#pragma unroll
    for (int j = 0; j < 4; ++j) acc[i][j] = vz;

  const int lrow = lane >> 2;
  const int kcol = (lane & 3) << 3;

  for (int kt = 0; kt < 4; ++kt) {          // K = 128
    __syncthreads();
    const int kbase = kt << 5;
#pragma unroll
    for (int jj = 0; jj < 2; ++jj) {
      const int c = (w << 1) + jj;
      const int m = (c << 4) + lrow;
      async_ld16(Ag + (size_t)(m0 + m) * D_ + kbase + kcol, &As[c << 9]);
      async_ld16(Wg + (size_t)(n0 + m) * D_ + kbase + kcol, &Bs[c << 9]);
    }
    __syncthreads();

    s16x8 af[4], bfr[4];
#pragma unroll
    for (int x = 0; x < 4; ++x) {
      af[x]  = *(const s16x8*)&As[((wm << 6) + (x << 4) + r) * 32 + (q << 3)];
      bfr[x] = *(const s16x8*)&Bs[((wn << 6) + (x << 4) + r) * 32 + (q << 3)];
    }
#pragma unroll
    for (int i = 0; i < 4; ++i)
#pragma unroll
      for (int j = 0; j < 4; ++j)
        acc[i][j] = __builtin_amdgcn_mfma_f32_16x16x32_bf16(af[i], bfr[j],
                                                            acc[i][j], 0, 0, 0);
  }

#pragma unroll
  for (int j = 0; j < 4; ++j) {
    const int gn = n0 + (wn << 6) + (j << 4) + r;
    const float bb = bias[gn];
#pragma unroll
    for (int i = 0; i < 4; ++i) {
      const int gmb = m0 + (wm << 6) + (i << 4) + (q << 2);
#pragma unroll
      for (int ii = 0; ii < 4; ++ii) {
        const int gm = gmb + ii;
        Og[(size_t)gm * H_ + gn] =
            __float2bfloat16(fmaxf(acc[i][j][ii] + bb, 0.f));
      }
    }
  }
}

// ---------------------------------------------------------------------------
// Persistent GRU scan, round-7:
//  * X(t+1) fragments burst-loaded into VGPRs at TOP of step t (issue order
//    ah -> ax so in-order vmcnt never stalls gh on HBM); consumed post-arrive
//    -> gi MFMAs are latency-free, HBM latency hidden under gh+gates.
//  * INVARIANT: the pre-arrive __syncthreads drains vmcnt(0), so when any
//    block passes barrier t, ALL blocks finished reading X slab t+1. This
//    licenses Vpart[t] (value-head partials) to alias X slab t (t>=1).
//  * Value head: per-block partial -> plain store Vpart[t][jt][row]; final
//    reduce kernel sums 32 partials + bv. No contended atomics in scan.
//  * h: t-indexed slabs, L3-direct packed agent stores, plain burst loads.
//  * Wih lane-packed LDS (48 KB); Whh B-frags in registers/AGPRs.
// ---------------------------------------------------------------------------
__global__ __launch_bounds__(256, 1)
void scan_kernel(const float* __restrict__ Wih32, const float* __restrict__ Whh32,
                 const float* __restrict__ bih, const float* __restrict__ bhh,
                 const float* __restrict__ Wv, short* __restrict__ Xs,
                 bf16* __restrict__ Hseq, float* __restrict__ Vp0,
                 unsigned* __restrict__ bar) {
  extern __shared__ short sm[];   // Wih lane-packed: 48 chunks x 512 shorts

  const int bid = blockIdx.x;
  const int rt = bid & 7, jt = bid >> 3;
  const int j0 = jt << 4;
  const int tid = threadIdx.x;
  const int w = tid >> 6, lane = tid & 63;
  const int r = lane & 15, q = lane >> 4;
  const int rw = (rt << 7) + (w << 5);   // wave's 32 rows

  // ---- Wih slice fp32 -> bf16, lane-packed into LDS (once) ----
#pragma unroll
  for (int i = 0; i < 12; ++i) {
    const int c = (i << 2) + w;          // chunk 0..47 = (g, kt)
    const int g = c >> 4, kt = c & 15;
    const s16x8 v = cvt8(Wih32 + (size_t)((g << 9) + j0 + r) * H_
                               + (kt << 5) + (q << 3));
    *(s16x8*)&sm[(c << 9) + (lane << 3)] = v;
  }

  // ---- Whh B-fragments fp32 -> bf16 registers (step-invariant) ----
  s16x8 whhf[3][16];
#pragma unroll
  for (int g = 0; g < 3; ++g)
#pragma unroll
    for (int kt = 0; kt < 16; ++kt)
      whhf[g][kt] = cvt8(Whh32 + (size_t)((g << 9) + j0 + r) * H_
                               + (kt << 5) + (q << 3));

  const int j = j0 + r;
  const float bR  = bih[j] + bhh[j];
  const float bZ  = bih[512 + j] + bhh[512 + j];
  const float bIN = bih[1024 + j];
  const float bHN = bhh[1024 + j];
  const float wvj = Wv[j];

  float hm[2][4] = {{0.f, 0.f, 0.f, 0.f}, {0.f, 0.f, 0.f, 0.f}};
  const f32x4 vz = {0.f, 0.f, 0.f, 0.f};

  const size_t aoff0 = (size_t)(rw + r) * H_ + (q << 3);
  const size_t aoff1 = aoff0 + (size_t)16 * H_;
  short* Hs = (short*)Hseq;

  __syncthreads();   // LDS staged

  // ---- prologue: load ax <- X slab 0, compute gi(0) ----
  s16x8 ax[16][2];
#pragma unroll
  for (int kt = 0; kt < 16; ++kt) {
    ax[kt][0] = ldg8(Xs + aoff0 + (kt << 5));
    ax[kt][1] = ldg8(Xs + aoff1 + (kt << 5));
  }
  f32x4 gia[3][2];
#pragma unroll
  for (int g = 0; g < 3; ++g) { gia[g][0] = vz; gia[g][1] = vz; }
#pragma unroll
  for (int kt = 0; kt < 16; ++kt)
#pragma unroll
    for (int g = 0; g < 3; ++g) {
      const s16x8 b = *(const s16x8*)&sm[(((g << 4) + kt) << 9) + (lane << 3)];
      gia[g][0] = __builtin_amdgcn_mfma_f32_16x16x32_bf16(ax[kt][0], b, gia[g][0], 0, 0, 0);
      gia[g][1] = __builtin_amdgcn_mfma_f32_16x16x32_bf16(ax[kt][1], b, gia[g][1], 0, 0, 0);
    }

  for (int t = 0; t < T_; ++t) {
    // ---- issue ah ring (L3, needed now) then ax burst (HBM, needed late) ----
    const short* hb = Hs + (size_t)(t - 1) * SLAB_;   // valid when t>0
    s16x8 ah[8][2];
    if (t > 0) {
#pragma unroll
      for (int p = 0; p < 8; ++p) {
        ah[p][0] = ldg8(hb + aoff0 + (p << 5));
        ah[p][1] = ldg8(hb + aoff1 + (p << 5));
      }
    }
    if (t < T_ - 1) {
      const short* xb = Xs + (size_t)(t + 1) * SLAB_;
#pragma unroll
      for (int kt = 0; kt < 16; ++kt) {
        ax[kt][0] = ldg8(xb + aoff0 + (kt << 5));
        ax[kt][1] = ldg8(xb + aoff1 + (kt << 5));
      }
    }

    // ---- gh MFMAs (register Whh), ah ring reload ----
    f32x4 gha[3][2];
#pragma unroll
    for (int g = 0; g < 3; ++g) { gha[g][0] = vz; gha[g][1] = vz; }
    if (t > 0) {
#pragma unroll
      for (int kt = 0; kt < 16; ++kt) {
        const int cur = kt & 7;
        const s16x8 a0 = ah[cur][0], a1 = ah[cur][1];
        if (kt < 8) {
          ah[cur][0] = ldg8(hb + aoff0 + ((kt + 8) << 5));
          ah[cur][1] = ldg8(hb + aoff1 + ((kt + 8) << 5));
        }
#pragma unroll
        for (int g = 0; g < 3; ++g) {
          gha[g][0] = __builtin_amdgcn_mfma_f32_16x16x32_bf16(a0, whhf[g][kt], gha[g][0], 0, 0, 0);
          gha[g][1] = __builtin_amdgcn_mfma_f32_16x16x32_bf16(a1, whhf[g][kt], gha[g][1], 0, 0, 0);
        }
      }
    }

    // ---- gates, h update, value partials ----
    short* hrow = Hs + (size_t)t * SLAB_;
    float* vp = (t == 0) ? Vp0 : (float*)(Xs + (size_t)t * SLAB_);
#pragma unroll
    for (int i = 0; i < 2; ++i)
#pragma unroll
      for (int ii = 0; ii < 4; ++ii) {
        const int row = rw + (i << 4) + (q << 2) + ii;
        const float rr = sigm(gia[0][i][ii] + gha[0][i][ii] + bR);
        const float zz = sigm(gia[1][i][ii] + gha[1][i][ii] + bZ);
        const float nn = tanh_f(gia[2][i][ii] + bIN + rr * (gha[2][i][ii] + bHN));
        const float hnew = (1.f - zz) * nn + zz * hm[i][ii];
        hm[i][ii] = hnew;
        // packed lane-pair L3-direct h store (cols j, j^1)
        const unsigned hv =
            (unsigned)(unsigned short)__builtin_bit_cast(unsigned short,
                                                         __float2bfloat16(hnew));
        const unsigned pv = (unsigned)__shfl_xor((int)hv, 1);
        if (t < T_ - 1 && !(r & 1)) {
          const unsigned pk = hv | (pv << 16);
          __hip_atomic_store((unsigned*)(hrow + (size_t)row * H_ + j0 + r), pk,
                             __ATOMIC_RELAXED, __HIP_MEMORY_SCOPE_AGENT);
        }
        float vpv = wvj * hnew;
        vpv += __shfl_xor(vpv, 1);
        vpv += __shfl_xor(vpv, 2);
        vpv += __shfl_xor(vpv, 4);
        vpv += __shfl_xor(vpv, 8);         // sum 16 j-lanes
        if (r == 0) vp[(jt << 10) + row] = vpv;   // plain, uncontended
      }

    if (t == T_ - 1) break;

    // ---- arrive (the syncthreads' vmcnt(0) drains h/vp stores AND ax reads
    //      of slab t+1 -- the Vpart-alias invariant) ----
    __syncthreads();
    if (tid == 0) atomicAdd(&bar[(bid & 63) << 4], 1u);

    // ---- gi(t+1): pure MFMA from prefetched ax (barrier shadow) ----
#pragma unroll
    for (int g = 0; g < 3; ++g) { gia[g][0] = vz; gia[g][1] = vz; }
#pragma unroll
    for (int kt = 0; kt < 16; ++kt)
#pragma unroll
      for (int g = 0; g < 3; ++g) {
        const s16x8 b = *(const s16x8*)&sm[(((g << 4) + kt) << 9) + (lane << 3)];
        gia[g][0] = __builtin_amdgcn_mfma_f32_16x16x32_bf16(ax[kt][0], b, gia[g][0], 0, 0, 0);
        gia[g][1] = __builtin_amdgcn_mfma_f32_16x16x32_bf16(ax[kt][1], b, gia[g][1], 0, 0, 0);
      }

    // ---- wait: wave0's 64 lanes poll the 64 padded counters ----
    if (w == 0) {
      const unsigned tgt = (unsigned)(t + 1) << 2;          // 4 blocks/counter
      unsigned spins = 0;
      while (true) {
        const unsigned v = __hip_atomic_load(&bar[lane << 4], __ATOMIC_RELAXED,
                                             __HIP_MEMORY_SCOPE_AGENT);
        if (__all(v >= tgt)) break;
        __builtin_amdgcn_s_sleep(2);
        if (++spins > 4000000u) break;                      // dead-man valve
      }
    }
    __syncthreads();
  }
}

// out[b][t][a] = bv + sum_jt Vpart[t][jt][row]
__global__ __launch_bounds__(256)
void out_kernel(const short* __restrict__ Xs, const float* __restrict__ Vp0,
                const float* __restrict__ bv, float* __restrict__ out) {
  const int o = blockIdx.x * 256 + threadIdx.x;   // 0..131071
  const int b = o >> 10, t = (o >> 3) & 127, a = o & 7;
  const int row = (b << 3) + a;
  const float* vp = (t == 0) ? Vp0 : (const float*)(Xs + (size_t)t * SLAB_);
  float s = bv[0];
#pragma unroll 8
  for (int jt = 0; jt < 32; ++jt) s += vp[(jt << 10) + row];
  out[o] = s;
}

extern "C" void kernel_launch(void* const* d_in, const int* in_sizes, int n_in,
                              void* d_out, int out_size, void* d_ws, size_t ws_size,
                              hipStream_t stream) {
  (void)in_sizes; (void)n_in; (void)out_size;
  const float* obs = (const float*)d_in[0];
  const float* W1  = (const float*)d_in[1];
  const float* b1  = (const float*)d_in[2];
  const float* Wih = (const float*)d_in[3];
  const float* bih = (const float*)d_in[4];
  const float* Whh = (const float*)d_in[5];
  const float* bhh = (const float*)d_in[6];
  const float* Wv  = (const float*)d_in[7];
  const float* bv  = (const float*)d_in[8];
  float* out = (float*)d_out;

  // ws (256 MiB): Hseq 127 slabs | X 128 slabs | spare slab: Vp0 + bar
  //   obsB aliases Hseq slabs 0..31, W1B slab 32 (dead before h writes)
  //   Vpart[t>=1] aliases X slab t (safe: pre-arrive vmcnt(0) drain)
  char* ws = (char*)d_ws;
  bf16*  Hseq = (bf16*)ws;                                  // 127 MiB
  bf16*  obsB = Hseq;
  bf16*  W1B  = Hseq + (size_t)32 * SLAB_;
  bf16*  X    = (bf16*)(ws + (size_t)127 * SLAB_ * 2);      // 128 MiB
  char*  spare = ws + (size_t)255 * SLAB_ * 2;              // 1 MiB
  float* Vp0  = (float*)spare;                              // 128 KiB
  unsigned* bar = (unsigned*)(spare + 512 * 1024);          // 4 KiB
  const size_t need = (size_t)256 * SLAB_ * 2;
  if (ws_size < need) {
    fprintf(stderr, "[kernel_launch] WS TOO SMALL: need %zu have %zu\n",
            need, ws_size);
    fflush(stderr);
  }

  hipFuncSetAttribute((const void*)scan_kernel,
                      hipFuncAttributeMaxDynamicSharedMemorySize, 98304);

  cvt_obs_kernel<<<16384, 256, 0, stream>>>(obs, obsB);
  cvt_kernel<<<64, 256, 0, stream>>>(W1, W1B);
  bar_init_kernel<<<4, 256, 0, stream>>>(bar);
  xgemm_kernel<<<4096, 256, 0, stream>>>(obsB, W1B, b1, X);
  // 96 KB dyn-LDS request (48 used) pins 1 block/CU -> 256 co-resident blocks
  scan_kernel<<<256, 256, 98304, stream>>>(Wih, Whh, bih, bhh, Wv, (short*)X,
                                           Hseq, Vp0, bar);
  out_kernel<<<512, 256, 0, stream>>>((const short*)X, Vp0, bv, out);
}

// Round 8
// 1700.973 us; speedup vs baseline: 1.4208x; 1.0530x over previous
//
#include <hip/hip_runtime.h>
#include <hip/hip_bf16.h>
#include <cstdio>
#include <cstdint>

#define BS_   128
#define T_    128
#define A_    8
#define D_    128
#define H_    512
#define ROWS_ 1024           // BS*A
#define MTOT_ 131072         // BS*T*A
#define SLAB_ (ROWS_ * H_)   // one timestep slab (X or h), elements

typedef __hip_bfloat16 bf16;
typedef __attribute__((ext_vector_type(4))) float f32x4;
typedef __attribute__((ext_vector_type(8))) short s16x8;
typedef __attribute__((ext_vector_type(4))) short s16x4;

__device__ __forceinline__ void async_ld16(const void* g, const void* lds) {
  __builtin_amdgcn_global_load_lds((const __attribute__((address_space(1))) void*)g,
                                   (__attribute__((address_space(3))) void*)lds,
                                   16, 0, 0);
}
__device__ __forceinline__ s16x8 ldg8(const short* p) { return *(const s16x8*)p; }
__device__ __forceinline__ float sigm(float x) { return 1.f / (1.f + __expf(-x)); }
__device__ __forceinline__ float tanh_f(float x) {
  const float e = __expf(2.f * x);            // inf-safe
  return 1.f - 2.f / (e + 1.f);
}
__device__ __forceinline__ s16x8 cvt8(const float* p) {
  const float4 a = ((const float4*)p)[0];
  const float4 b = ((const float4*)p)[1];
  s16x8 r_;
  r_[0] = __builtin_bit_cast(short, __float2bfloat16(a.x));
  r_[1] = __builtin_bit_cast(short, __float2bfloat16(a.y));
  r_[2] = __builtin_bit_cast(short, __float2bfloat16(a.z));
  r_[3] = __builtin_bit_cast(short, __float2bfloat16(a.w));
  r_[4] = __builtin_bit_cast(short, __float2bfloat16(b.x));
  r_[5] = __builtin_bit_cast(short, __float2bfloat16(b.y));
  r_[6] = __builtin_bit_cast(short, __float2bfloat16(b.z));
  r_[7] = __builtin_bit_cast(short, __float2bfloat16(b.w));
  return r_;
}

// obs [b][t][a][d] fp32 -> obsB [t][b*8+a][d] bf16
__global__ __launch_bounds__(256)
void cvt_obs_kernel(const float* __restrict__ src, bf16* __restrict__ dst) {
  const int o = (blockIdx.x * 256 + threadIdx.x) << 2;
  const int d = o & 127, a = (o >> 7) & 7, t = (o >> 10) & 127, b = o >> 17;
  const float4 v = *(const float4*)(src + o);
  s16x4 pk;
  pk[0] = __builtin_bit_cast(short, __float2bfloat16(v.x));
  pk[1] = __builtin_bit_cast(short, __float2bfloat16(v.y));
  pk[2] = __builtin_bit_cast(short, __float2bfloat16(v.z));
  pk[3] = __builtin_bit_cast(short, __float2bfloat16(v.w));
  *(s16x4*)((short*)dst + ((((size_t)t << 10) + (b << 3) + a) << 7) + d) = pk;
}

__global__ __launch_bounds__(256)
void cvt_kernel(const float* __restrict__ src, bf16* __restrict__ dst) {
  const int i = (blockIdx.x * 256 + threadIdx.x) << 2;
  const float4 v = *(const float4*)(src + i);
  s16x4 o;
  o[0] = __builtin_bit_cast(short, __float2bfloat16(v.x));
  o[1] = __builtin_bit_cast(short, __float2bfloat16(v.y));
  o[2] = __builtin_bit_cast(short, __float2bfloat16(v.z));
  o[3] = __builtin_bit_cast(short, __float2bfloat16(v.w));
  *(s16x4*)((short*)dst + i) = o;
}

__global__ __launch_bounds__(256)
void bar_init_kernel(unsigned* __restrict__ bar) {
  const int i = blockIdx.x * 256 + threadIdx.x;
  if (i < 256) bar[i] = 0u;
}

// ---------------------------------------------------------------------------
// X = relu(obsB @ W1^T + b1)
// ---------------------------------------------------------------------------
__global__ __launch_bounds__(256)
void xgemm_kernel(const bf16* __restrict__ Ag, const bf16* __restrict__ Wg,
                  const float* __restrict__ bias, bf16* __restrict__ Og) {
  const int bid = blockIdx.x;
  const int m0 = (bid >> 2) << 7;
  const int n0 = (bid & 3) << 7;
  const int tid = threadIdx.x;
  const int w = tid >> 6, lane = tid & 63;
  const int r = lane & 15, q = lane >> 4;
  const int wm = w & 1, wn = w >> 1;

  __shared__ short As[128 * 32];
  __shared__ short Bs[128 * 32];

  f32x4 acc[4][4];
  const f32x4 vz = {0.f, 0.f, 0.f, 0.f};
#pragma unroll
  for (int i = 0; i < 4; ++i)
#pragma unroll
    for (int j = 0; j < 4; ++j) acc[i][j] = vz;

  const int lrow = lane >> 2;
  const int kcol = (lane & 3) << 3;

  for (int kt = 0; kt < 4; ++kt) {          // K = 128
    __syncthreads();
    const int kbase = kt << 5;
#pragma unroll
    for (int jj = 0; jj < 2; ++jj) {
      const int c = (w << 1) + jj;
      const int m = (c << 4) + lrow;
      async_ld16(Ag + (size_t)(m0 + m) * D_ + kbase + kcol, &As[c << 9]);
      async_ld16(Wg + (size_t)(n0 + m) * D_ + kbase + kcol, &Bs[c << 9]);
    }
    __syncthreads();

    s16x8 af[4], bfr[4];
#pragma unroll
    for (int x = 0; x < 4; ++x) {
      af[x]  = *(const s16x8*)&As[((wm << 6) + (x << 4) + r) * 32 + (q << 3)];
      bfr[x] = *(const s16x8*)&Bs[((wn << 6) + (x << 4) + r) * 32 + (q << 3)];
    }
#pragma unroll
    for (int i = 0; i < 4; ++i)
#pragma unroll
      for (int j = 0; j < 4; ++j)
        acc[i][j] = __builtin_amdgcn_mfma_f32_16x16x32_bf16(af[i], bfr[j],
                                                            acc[i][j], 0, 0, 0);
  }

#pragma unroll
  for (int j = 0; j < 4; ++j) {
    const int gn = n0 + (wn << 6) + (j << 4) + r;
    const float bb = bias[gn];
#pragma unroll
    for (int i = 0; i < 4; ++i) {
      const int gmb = m0 + (wm << 6) + (i << 4) + (q << 2);
#pragma unroll
      for (int ii = 0; ii < 4; ++ii) {
        const int gm = gmb + ii;
        Og[(size_t)gm * H_ + gn] =
            __float2bfloat16(fmaxf(acc[i][j][ii] + bb, 0.f));
      }
    }
  }
}

// ---------------------------------------------------------------------------
// Persistent GRU scan, round-8: GROUP-LOCAL barriers.
//  * Rows are independent across rt-groups: block (rt=bid&7, jt=bid>>3) reads
//    h only for rows rt*128..+127, produced solely by the 32 blocks sharing
//    rt. So sync is per-group: ONE counter, 32 arrivals, single-poll detect.
//    8 groups drift freely -- no 256-wide grid barrier (round<=7's ~13us/step
//    floor was that barrier).
//  * Value head REMOVED from the steady-state loop: v(t)=Wv.h_t+bv is
//    recomputed from stored Hseq by out_kernel; only t=127 (h unstored)
//    writes register partials to Vp127.
//  * h: t-indexed slabs (virgin addresses -> no stale caches), L3-direct
//    packed agent stores, plain burst loads; drain via pre-arrive
//    __syncthreads vmcnt(0).
//  * Wih lane-packed LDS; Whh B-frags in registers; ah ring-8, ax ring-4
//    (ax issued in the arrive-shadow of the PREVIOUS step, so ah waits never
//    queue behind X traffic).
// ---------------------------------------------------------------------------
__global__ __launch_bounds__(256, 1)
void scan_kernel(const float* __restrict__ Wih32, const float* __restrict__ Whh32,
                 const float* __restrict__ bih, const float* __restrict__ bhh,
                 const float* __restrict__ Wv, const short* __restrict__ Xs,
                 bf16* __restrict__ Hseq, float* __restrict__ Vp127,
                 unsigned* __restrict__ bar) {
  extern __shared__ short sm[];   // Wih lane-packed: 48 chunks x 512 shorts

  const int bid = blockIdx.x;
  const int rt = bid & 7, jt = bid >> 3;
  const int j0 = jt << 4;
  const int tid = threadIdx.x;
  const int w = tid >> 6, lane = tid & 63;
  const int r = lane & 15, q = lane >> 4;
  const int rw = (rt << 7) + (w << 5);   // wave's 32 rows
  unsigned* barc = &bar[rt << 5];        // group counter, 128B padded

  // ---- Wih slice fp32 -> bf16, lane-packed into LDS (once) ----
#pragma unroll
  for (int i = 0; i < 12; ++i) {
    const int c = (i << 2) + w;          // chunk 0..47 = (g, kt)
    const int g = c >> 4, kt = c & 15;
    const s16x8 v = cvt8(Wih32 + (size_t)((g << 9) + j0 + r) * H_
                               + (kt << 5) + (q << 3));
    *(s16x8*)&sm[(c << 9) + (lane << 3)] = v;
  }

  // ---- Whh B-fragments fp32 -> bf16 registers (step-invariant) ----
  s16x8 whhf[3][16];
#pragma unroll
  for (int g = 0; g < 3; ++g)
#pragma unroll
    for (int kt = 0; kt < 16; ++kt)
      whhf[g][kt] = cvt8(Whh32 + (size_t)((g << 9) + j0 + r) * H_
                               + (kt << 5) + (q << 3));

  const int j = j0 + r;
  const float bR  = bih[j] + bhh[j];
  const float bZ  = bih[512 + j] + bhh[512 + j];
  const float bIN = bih[1024 + j];
  const float bHN = bhh[1024 + j];
  const float wvj = Wv[j];

  float hm[2][4] = {{0.f, 0.f, 0.f, 0.f}, {0.f, 0.f, 0.f, 0.f}};
  const f32x4 vz = {0.f, 0.f, 0.f, 0.f};

  const size_t aoff0 = (size_t)(rw + r) * H_ + (q << 3);
  const size_t aoff1 = aoff0 + (size_t)16 * H_;
  short* Hs = (short*)Hseq;

  __syncthreads();   // LDS staged

  // ---- prologue: gi(0) from X slab 0, ring-4 ----
  f32x4 gia[3][2];
#pragma unroll
  for (int g = 0; g < 3; ++g) { gia[g][0] = vz; gia[g][1] = vz; }
  {
    s16x8 ax[4][2];
#pragma unroll
    for (int p = 0; p < 3; ++p) {
      ax[p][0] = ldg8(Xs + aoff0 + (p << 5));
      ax[p][1] = ldg8(Xs + aoff1 + (p << 5));
    }
#pragma unroll
    for (int kt = 0; kt < 16; ++kt) {
      const int cur = kt & 3;
      if (kt < 13) {
        const int np = (kt + 3) & 3;
        ax[np][0] = ldg8(Xs + aoff0 + ((kt + 3) << 5));
        ax[np][1] = ldg8(Xs + aoff1 + ((kt + 3) << 5));
      }
#pragma unroll
      for (int g = 0; g < 3; ++g) {
        const s16x8 b = *(const s16x8*)&sm[(((g << 4) + kt) << 9) + (lane << 3)];
        gia[g][0] = __builtin_amdgcn_mfma_f32_16x16x32_bf16(ax[cur][0], b, gia[g][0], 0, 0, 0);
        gia[g][1] = __builtin_amdgcn_mfma_f32_16x16x32_bf16(ax[cur][1], b, gia[g][1], 0, 0, 0);
      }
    }
  }

  for (int t = 0; t < T_; ++t) {
    // ---- group wait (h slab t-1 complete within this rt-group) ----
    f32x4 gha[3][2];
#pragma unroll
    for (int g = 0; g < 3; ++g) { gha[g][0] = vz; gha[g][1] = vz; }
    if (t > 0) {
      if (tid == 0) {
        const unsigned tgt = (unsigned)t << 5;              // 32*t
        unsigned spins = 0;
        while (__hip_atomic_load(barc, __ATOMIC_RELAXED,
                                 __HIP_MEMORY_SCOPE_AGENT) < tgt) {
          __builtin_amdgcn_s_sleep(1);
          if (++spins > 8000000u) break;                    // dead-man valve
        }
      }
      __syncthreads();

      // ---- gh: ah ring-8 from Hseq[t-1] + register Whh ----
      const short* hb = Hs + (size_t)(t - 1) * SLAB_;
      s16x8 ah[8][2];
#pragma unroll
      for (int p = 0; p < 8; ++p) {
        ah[p][0] = ldg8(hb + aoff0 + (p << 5));
        ah[p][1] = ldg8(hb + aoff1 + (p << 5));
      }
#pragma unroll
      for (int kt = 0; kt < 16; ++kt) {
        const int cur = kt & 7;
        const s16x8 a0 = ah[cur][0], a1 = ah[cur][1];
        if (kt < 8) {
          ah[cur][0] = ldg8(hb + aoff0 + ((kt + 8) << 5));
          ah[cur][1] = ldg8(hb + aoff1 + ((kt + 8) << 5));
        }
#pragma unroll
        for (int g = 0; g < 3; ++g) {
          gha[g][0] = __builtin_amdgcn_mfma_f32_16x16x32_bf16(a0, whhf[g][kt], gha[g][0], 0, 0, 0);
          gha[g][1] = __builtin_amdgcn_mfma_f32_16x16x32_bf16(a1, whhf[g][kt], gha[g][1], 0, 0, 0);
        }
      }
    }

    // ---- gates, h update; t=127: value partials from registers ----
    short* hrow = Hs + (size_t)t * SLAB_;
    const bool last = (t == T_ - 1);
#pragma unroll
    for (int i = 0; i < 2; ++i)
#pragma unroll
      for (int ii = 0; ii < 4; ++ii) {
        const int row = rw + (i << 4) + (q << 2) + ii;
        const float rr = sigm(gia[0][i][ii] + gha[0][i][ii] + bR);
        const float zz = sigm(gia[1][i][ii] + gha[1][i][ii] + bZ);
        const float nn = tanh_f(gia[2][i][ii] + bIN + rr * (gha[2][i][ii] + bHN));
        const float hnew = (1.f - zz) * nn + zz * hm[i][ii];
        hm[i][ii] = hnew;
        if (!last) {
          // packed lane-pair L3-direct h store (cols j, j^1)
          const unsigned hv =
              (unsigned)(unsigned short)__builtin_bit_cast(unsigned short,
                                                           __float2bfloat16(hnew));
          const unsigned pv = (unsigned)__shfl_xor((int)hv, 1);
          if (!(r & 1)) {
            const unsigned pk = hv | (pv << 16);
            __hip_atomic_store((unsigned*)(hrow + (size_t)row * H_ + j0 + r), pk,
                               __ATOMIC_RELAXED, __HIP_MEMORY_SCOPE_AGENT);
          }
        } else {
          float vpv = wvj * hnew;
          vpv += __shfl_xor(vpv, 1);
          vpv += __shfl_xor(vpv, 2);
          vpv += __shfl_xor(vpv, 4);
          vpv += __shfl_xor(vpv, 8);       // sum 16 j-lanes
          if (r == 0) Vp127[(jt << 10) + row] = vpv;
        }
      }

    if (last) break;

    // ---- arrive: syncthreads drains h stores (vmcnt0), then flag ----
    __syncthreads();
    if (tid == 0) atomicAdd(barc, 1u);

    // ---- gi(t+1) in the arrive-shadow: ring-4 from X (L2-warm) ----
#pragma unroll
    for (int g = 0; g < 3; ++g) { gia[g][0] = vz; gia[g][1] = vz; }
    {
      const short* xb = Xs + (size_t)(t + 1) * SLAB_;
      s16x8 ax[4][2];
#pragma unroll
      for (int p = 0; p < 3; ++p) {
        ax[p][0] = ldg8(xb + aoff0 + (p << 5));
        ax[p][1] = ldg8(xb + aoff1 + (p << 5));
      }
#pragma unroll
      for (int kt = 0; kt < 16; ++kt) {
        const int cur = kt & 3;
        if (kt < 13) {
          const int np = (kt + 3) & 3;
          ax[np][0] = ldg8(xb + aoff0 + ((kt + 3) << 5));
          ax[np][1] = ldg8(xb + aoff1 + ((kt + 3) << 5));
        }
#pragma unroll
        for (int g = 0; g < 3; ++g) {
          const s16x8 b = *(const s16x8*)&sm[(((g << 4) + kt) << 9) + (lane << 3)];
          gia[g][0] = __builtin_amdgcn_mfma_f32_16x16x32_bf16(ax[cur][0], b, gia[g][0], 0, 0, 0);
          gia[g][1] = __builtin_amdgcn_mfma_f32_16x16x32_bf16(ax[cur][1], b, gia[g][1], 0, 0, 0);
        }
      }
    }
  }
}

// ---------------------------------------------------------------------------
// out[b][t][a] = bv + Wv . h_t(row)  (h from Hseq for t<127, Vp127 for t=127)
// block = (t, rowgroup of 8); thread (r8=tid>>5, c=tid&31): cols c*16..+15
// ---------------------------------------------------------------------------
__global__ __launch_bounds__(256)
void out_kernel(const bf16* __restrict__ Hseq, const float* __restrict__ Vp127,
                const float* __restrict__ Wv, const float* __restrict__ bv,
                float* __restrict__ out) {
  __shared__ float wvs[512];
  const int bid = blockIdx.x;           // 0..16383
  const int t = bid >> 7, rg = bid & 127;
  const int tid = threadIdx.x;
  const int r8 = tid >> 5, c = tid & 31;
  const int row = (rg << 3) + r8;
  if (tid < 128) *(float4*)&wvs[tid << 2] = *(const float4*)&Wv[tid << 2];
  __syncthreads();

  float s = 0.f;
  if (t < T_ - 1) {
    const short* hp = (const short*)Hseq + (size_t)t * SLAB_ + ((size_t)row << 9)
                    + (c << 4);
    const s16x8 h0 = ldg8(hp), h1 = ldg8(hp + 8);
    const float* wp = &wvs[c << 4];
#pragma unroll
    for (int k = 0; k < 8; ++k)
      s += wp[k] * __bfloat162float(__builtin_bit_cast(__hip_bfloat16, (unsigned short)h0[k]));
#pragma unroll
    for (int k = 0; k < 8; ++k)
      s += wp[8 + k] * __bfloat162float(__builtin_bit_cast(__hip_bfloat16, (unsigned short)h1[k]));
  } else {
    s = Vp127[(c << 10) + row];          // 32 partials, one per lane
  }
  s += __shfl_xor(s, 1);
  s += __shfl_xor(s, 2);
  s += __shfl_xor(s, 4);
  s += __shfl_xor(s, 8);
  s += __shfl_xor(s, 16);               // sum over 32 c-lanes
  if (c == 0)
    out[((row >> 3) << 10) + (t << 3) + (row & 7)] = s + bv[0];
}

extern "C" void kernel_launch(void* const* d_in, const int* in_sizes, int n_in,
                              void* d_out, int out_size, void* d_ws, size_t ws_size,
                              hipStream_t stream) {
  (void)in_sizes; (void)n_in; (void)out_size;
  const float* obs = (const float*)d_in[0];
  const float* W1  = (const float*)d_in[1];
  const float* b1  = (const float*)d_in[2];
  const float* Wih = (const float*)d_in[3];
  const float* bih = (const float*)d_in[4];
  const float* Whh = (const float*)d_in[5];
  const float* bhh = (const float*)d_in[6];
  const float* Wv  = (const float*)d_in[7];
  const float* bv  = (const float*)d_in[8];
  float* out = (float*)d_out;

  // ws (256 MiB): Hseq 127 slabs | X 128 slabs | spare 1 MiB (Vp127 + bar)
  //   obsB aliases Hseq slabs 0..31, W1B slab 32 (dead before h writes)
  char* ws = (char*)d_ws;
  bf16*  Hseq = (bf16*)ws;                                  // 127 MiB
  bf16*  obsB = Hseq;
  bf16*  W1B  = Hseq + (size_t)32 * SLAB_;
  bf16*  X    = (bf16*)(ws + (size_t)127 * SLAB_ * 2);      // 128 MiB
  char*  spare = ws + (size_t)255 * SLAB_ * 2;              // 1 MiB
  float* Vp127 = (float*)spare;                             // 128 KiB
  unsigned* bar = (unsigned*)(spare + 256 * 1024);          // 8 padded ctrs
  const size_t need = (size_t)256 * SLAB_ * 2;
  if (ws_size < need) {
    fprintf(stderr, "[kernel_launch] WS TOO SMALL: need %zu have %zu\n",
            need, ws_size);
    fflush(stderr);
  }

  hipFuncSetAttribute((const void*)scan_kernel,
                      hipFuncAttributeMaxDynamicSharedMemorySize, 98304);

  cvt_obs_kernel<<<16384, 256, 0, stream>>>(obs, obsB);
  cvt_kernel<<<64, 256, 0, stream>>>(W1, W1B);
  bar_init_kernel<<<1, 256, 0, stream>>>(bar);
  xgemm_kernel<<<4096, 256, 0, stream>>>(obsB, W1B, b1, X);
  // 96 KB dyn-LDS request (48 used) pins 1 block/CU -> 256 co-resident blocks
  scan_kernel<<<256, 256, 98304, stream>>>(Wih, Whh, bih, bhh, Wv, (const short*)X,
                                           Hseq, Vp127, bar);
  out_kernel<<<16384, 256, 0, stream>>>(Hseq, Vp127, Wv, bv, out);
}